// Round 8
// baseline (49.944 us; speedup 1.0000x reference)
//
#include <hip/hip_runtime.h>
#include <math.h>

#define HS 1024
#define WS 1024
#define KK 24
#define KD 35
#define NF 35
#define NDP 69              // dp in [-34,34]
#define NGRP 23             // dp-groups per (b,k): 69/23 = 3 iters exactly; grid 1104 = 4.3 blocks/CU
#define CROW 42             // padded C row stride (cols 35..41 = zero pad)
#define NCHUNK 38           // 5-u chunks over the triangular (dq-tile,u) domain
#define PRS 10              // partR per-lane stride (floats); even -> aligned float2

// ws byte offsets
#define G_OFF    0u                     // [35][1024] float2 = 286720 B
#define CROP_OFF 286720u                // [35][35] float2   = 9800 B
#define D_OFF    296520u                // [2][69][35] float2 = 38640 B
#define ZERO_QWORDS 6055                // (9800 + 38640) / 8, crop+D contiguous

// ---- K1: mask row x -> pool3+sigmoid -> column DFT (Hermitian: 18 freqs) ----
// Radix-4 fold + Chebyshev rotator advance (w_{n+1} = 2cos*w_n - w_{n-1}: 2 FMA vs 4).
// Also zeroes crop+D (blocks 0..23); kernel boundary makes it coherent for K2/K3.
__global__ __launch_bounds__(256) void k_maskG(const float* __restrict__ ms,
                                               float2* __restrict__ G,
                                               unsigned long long* __restrict__ zq) {
    __shared__ float cs[WS + 8];        // column sums at cs[4+j]; cs[3] and cs[4+WS] are zero guards
    __shared__ float m[WS];
    __shared__ float2 part[252];
    const int x = blockIdx.x;
    const int t = threadIdx.x;

    if (x < 24) {
        int i = x * 256 + t;
        if (i < ZERO_QWORDS) zq[i] = 0ull;
    }
    {   // vertical 3-sum, float4: each thread owns j = 4t..4t+3 (exactly covers WS)
        const int j = 4 * t;
        float4 b = *(const float4*)&ms[x * WS + j];
        float4 a = make_float4(0.f, 0.f, 0.f, 0.f);
        float4 d = make_float4(0.f, 0.f, 0.f, 0.f);
        if (x > 0)      a = *(const float4*)&ms[(x - 1) * WS + j];
        if (x < HS - 1) d = *(const float4*)&ms[(x + 1) * WS + j];
        float4 s;
        s.x = a.x + b.x + d.x;
        s.y = a.y + b.y + d.y;
        s.z = a.z + b.z + d.z;
        s.w = a.w + b.w + d.w;
        *(float4*)&cs[4 + j] = s;
        if (t == 0) { cs[3] = 0.0f; cs[4 + WS] = 0.0f; }
    }
    __syncthreads();
    {   // horizontal 3-sum + sigmoid, float4
        const int j = 4 * t;
        float4 c = *(const float4*)&cs[4 + j];
        float l = cs[3 + j];
        float r = cs[8 + j];
        float p0 = (l   + c.x + c.y) * (1.0f / 9.0f);
        float p1 = (c.x + c.y + c.z) * (1.0f / 9.0f);
        float p2 = (c.y + c.z + c.w) * (1.0f / 9.0f);
        float p3 = (c.z + c.w + r  ) * (1.0f / 9.0f);
        float4 mv;
        mv.x = 1.0f / (1.0f + expf(-4.0f * (p0 - 0.5f)));
        mv.y = 1.0f / (1.0f + expf(-4.0f * (p1 - 0.5f)));
        mv.z = 1.0f / (1.0f + expf(-4.0f * (p2 - 0.5f)));
        mv.w = 1.0f / (1.0f + expf(-4.0f * (p3 - 0.5f)));
        *(float4*)&m[j] = mv;
    }
    __syncthreads();
    if (t < 252) {                                   // 18 freqs (v=0..17) x 14 segments
        const int qi = t / 14, seg = t % 14;
        float si, ci, ss, cc;
        sincospif(-(float)(qi * seg) * (1.0f / 512.0f), &si, &ci);
        sincospif(-(float)(qi * 14)  * (1.0f / 512.0f), &ss, &cc);
        const float s2 = (qi & 1) ? -1.0f : 1.0f;    // (-1)^qi
        const int qm = qi & 3;                       // e1 = (-i)^qi
        const float er = (qm == 0) ? 1.0f : (qm == 2) ? -1.0f : 0.0f;
        const float ei = (qm == 1) ? -1.0f : (qm == 3) ? 1.0f : 0.0f;
        const float tc = 2.0f * cc;                  // Chebyshev coefficient
        float wr = ci, wi = si;                      // w_0
        float pr = ci * cc + si * ss;                // w_{-1} = w_0 * conj(step)
        float pi = si * cc - ci * ss;
        float re = 0.0f, im = 0.0f;
        for (int y = seg; y < 256; y += 14) {
            float m0 = m[y], m1 = m[y + 256], m2 = m[y + 512], m3 = m[y + 768];
            float A  = fmaf(s2, m2, m0);             // fold = (m0 + s2 m2) + e1*(m1 + s2 m3)
            float Bv = fmaf(s2, m3, m1);
            float tre = fmaf(er, Bv, A);
            float tim = ei * Bv;
            re += tre * wr - tim * wi;               // (fold) * w^y
            im += tre * wi + tim * wr;
            float nr = tc * wr - pr;                 // Chebyshev advance
            float ni = tc * wi - pi;
            pr = wr; pi = wi; wr = nr; wi = ni;
        }
        part[t] = make_float2(re, im);
    }
    __syncthreads();
    if (t < 18) {
        float re = 0.0f, im = 0.0f;
        for (int s = 0; s < 14; ++s) { float2 p = part[t * 14 + s]; re += p.x; im += p.y; }
        G[(17 + t) * HS + x] = make_float2(re, im);
        if (t > 0) G[(17 - t) * HS + x] = make_float2(re, -im);   // Hermitian mirror (m real)
    }
}

// ---- K2: crop[p][q] += partial DFT over 64-long x-segment (35 q x 16 segs = 560 blocks) ----
// Chebyshev rotator; 16 segments (32 regressed in R5 -> atomic contention suspect).
__global__ __launch_bounds__(256) void k_crop(const float2* __restrict__ G,
                                              float2* __restrict__ crop) {
    __shared__ float2 g2[64];
    __shared__ float2 part[245];
    const int q  = blockIdx.x >> 4;
    const int xs = (blockIdx.x & 15) * 64;
    const int t  = threadIdx.x;
    if (t < 64) g2[t] = G[q * HS + xs + t];
    __syncthreads();
    if (t < 245) {
        const int p = t / 7, seg = t % 7;
        const int v = p - 17;
        float si, ci, ss, cc;
        sincospif((float)(v * (xs + seg)) * (1.0f / 512.0f), &si, &ci);
        sincospif((float)(v * 7)          * (1.0f / 512.0f), &ss, &cc);
        const float tc = 2.0f * cc;
        float wr = ci, wi = si;
        float pr = ci * cc + si * ss;                // w_{-1}
        float pi = si * cc - ci * ss;
        float re = 0.0f, im = 0.0f;
        for (int r = seg; r < 64; r += 7) {
            float2 gv = g2[r];
            re += gv.x * wr + gv.y * wi;     // g * conj(w)
            im += gv.y * wr - gv.x * wi;
            float nr = tc * wr - pr;
            float ni = tc * wi - pi;
            pr = wr; pi = wi; wr = nr; wi = ni;
        }
        part[t] = make_float2(re, im);
    }
    __syncthreads();
    if (t < NF) {
        float re = 0.0f, im = 0.0f;
        for (int s = 0; s < 7; ++s) { float2 p2 = part[t * 7 + s]; re += p2.x; im += p2.y; }
        float* dst = (float*)&crop[t * NF + q];
        atomicAdd(dst,     re);              // device-scope -> coherent point
        atomicAdd(dst + 1, im);
    }
}

// ---- K3: D[b][dp][dq] += sk * autocorr(C); block = (b,k,dp-group) ----
// Flattened chunk list, lane = chunk*6+pgrp, 228 equal-work lanes, p-stride 6; sliding
// window (2 LDS reads / 4 cMACs); partR double-buffered, 1 barrier/dp.
// NGRP=23: exactly 3 dp-iters per block, grid 1104 -> 4-5 blocks/CU for bubble hiding.
// Reduce round-robin: iter i's reduce runs on wave (i&3) only -> the MAC+reduce serial
// straggler hits each wave 1-in-4 iters instead of wave 0 every iter. (All-waves-reduce
// regressed in R5: every wave then paid the full reduce.) Double-buffer makes it safe:
// iter i+1's barrier orders reduce(buf[i&1]) before iter i+2 rewrites that buf.
__global__ __launch_bounds__(256) void k_D(
    const float2* __restrict__ crop,
    const float* __restrict__ kre0, const float* __restrict__ kim0,
    const float* __restrict__ kre1, const float* __restrict__ kim1,
    const float* __restrict__ sc0,  const float* __restrict__ sc1,
    float2* __restrict__ D)
{
    __shared__ float2 C[KD * CROW];
    __shared__ float partRf[2][NCHUNK * 6 * PRS];    // [buf][lane*PRS + 2c(+1)]
    const int tup = blockIdx.x;
    const int t   = threadIdx.x;

    const int b   = tup / (KK * NGRP);
    const int rem = tup % (KK * NGRP);
    const int k   = rem / NGRP;
    const int g   = rem % NGRP;
    const float* kre = b ? kre1 : kre0;
    const float* kim = b ? kim1 : kim0;
    const float dosefac = (b ? 0.98f : 1.0f) * (1.0f / 1048576.0f);
    const float sk2 = ((b ? sc1 : sc0)[k]) * dosefac * dosefac;   // dose^2 / N^4 folded

    // zero the C pad (cols 35..41); products against pad vanish -> no bound checks
    if (t < 245) C[(t / 7) * CROW + 35 + (t % 7)] = make_float2(0.0f, 0.0f);
    #pragma unroll
    for (int j = 0; j < 5; ++j) {                // stage C = crop .* kernel (unscaled)
        int i = t + j * 256;
        if (i < KD * KD) {
            float2 c = crop[i];                  // global, L2-cached across blocks
            int row = i / 35, col = i % 35;
            float kr = kre[k * KD * KD + i], ki = kim[k * KD * KD + i];
            C[row * CROW + col] = make_float2(c.x * kr - c.y * ki,
                                              c.x * ki + c.y * kr);
        }
    }
    __syncthreads();

    // lane -> (chunk, pgrp); chunk -> (tau, uchunk) via cb = {0,7,14,20,25,29,32,35,37}
    const int ch = t / 6;
    const int pg = t % 6;
    const bool act = (ch < NCHUNK);
    const int tau = (ch >= 7) + (ch >= 14) + (ch >= 20) + (ch >= 25)
                  + (ch >= 29) + (ch >= 32) + (ch >= 35) + (ch >= 37);
    const int cbt = (tau == 0) ? 0 : (tau == 1) ? 7 : (tau == 2) ? 14 : (tau == 3) ? 20
                  : (tau == 4) ? 25 : (tau == 5) ? 29 : (tau == 6) ? 32 : (tau == 7) ? 35 : 37;
    const int d0 = 4 * tau;
    const int u0 = 5 * (ch - cbt);               // act => d0+u0+7 <= 41 (pad bound)

    // reduce-lane lookup: lane (t&63) -> dq; reducing wave rotates per iter
    const int lw  = t >> 6;                      // wave id 0..3
    const int ln  = t & 63;                      // lane in wave
    const int tau2 = ln >> 2;
    const int cb2 = (tau2 == 0) ? 0 : (tau2 == 1) ? 7 : (tau2 == 2) ? 14 : (tau2 == 3) ? 20
                  : (tau2 == 4) ? 25 : (tau2 == 5) ? 29 : (tau2 == 6) ? 32 : (tau2 == 7) ? 35 : 37;
    const int cn2 = (tau2 == 0) ? 7 : (tau2 == 1) ? 7 : (tau2 == 2) ? 6 : (tau2 == 3) ? 5
                  : (tau2 == 4) ? 4 : (tau2 == 5) ? 3 : (tau2 == 6) ? 3 : (tau2 == 7) ? 2 : 1;
    const int s0 = cb2 * 6, cnt = cn2 * 6, c2 = (ln & 3) * 2;

    int pb = 0;
    int it = 0;
    for (int idp = g; idp < NDP; idp += NGRP, ++it) {
        const int dp = idp - 34;
        if (act) {
            const int plo = max(0, dp), phi = min(34, 34 + dp);
            float2 ac0 = {0,0}, ac1 = {0,0}, ac2 = {0,0}, ac3 = {0,0};
            for (int p = plo + pg; p <= phi; p += 6) {
                const float2* rowa = &C[p * CROW + d0 + u0];
                const float2* rowb = &C[(p - dp) * CROW + u0];
                float2 a0 = rowa[0], a1 = rowa[1], a2 = rowa[2];
                #pragma unroll
                for (int s = 0; s < 5; ++s) {
                    float2 a3 = rowa[s + 3];     // max col 41 -> pad, zero
                    float2 bb = rowb[s];         // max col 34 -> real; a-pad kills overrun
                    ac0.x += a0.x * bb.x + a0.y * bb.y;  ac0.y += a0.y * bb.x - a0.x * bb.y;
                    ac1.x += a1.x * bb.x + a1.y * bb.y;  ac1.y += a1.y * bb.x - a1.x * bb.y;
                    ac2.x += a2.x * bb.x + a2.y * bb.y;  ac2.y += a2.y * bb.x - a2.x * bb.y;
                    ac3.x += a3.x * bb.x + a3.y * bb.y;  ac3.y += a3.y * bb.x - a3.x * bb.y;
                    a0 = a1; a1 = a2; a2 = a3;   // window shift (renamed away by unroll)
                }
            }
            float* pr = &partRf[pb][t * PRS];
            *(float2*)&pr[0] = ac0;
            *(float2*)&pr[2] = ac1;
            *(float2*)&pr[4] = ac2;
            *(float2*)&pr[6] = ac3;
        }
        __syncthreads();
        if (lw == (it & 3) && ln < NF) {         // dq = ln; rotating reduce wave
            float re = 0.0f, im = 0.0f;
            for (int j = 0; j < cnt; ++j) {
                const float2 v = *(const float2*)&partRf[pb][(s0 + j) * PRS + c2];
                re += v.x; im += v.y;
            }
            float* dst = (float*)&D[(b * NDP + idp) * NF + ln];
            atomicAdd(dst,     re * sk2);
            atomicAdd(dst + 1, im * sk2);
        }
        pb ^= 1;                                 // next iter writes other buf; its barrier
    }                                            // protects this buf before re-write
}

// ---- K4: per row x: B_x[dq] = sum_dp D[dp][dq] e(dp x) (3-way split); then pixels ----
// Pixels y = t + 256j: e(dq*y) = e(dq*t) * i^(dq*j). Accumulate S[dq&3] directly;
// apply the i^(m*j) twist once in the epilogue. Chebyshev rotator in both phases.
// Per dq in the pixel loop: 8 FMA accum + 2 cheb + 1 b128 read = 11 insts.
// NOTE: k_final is at its HBM write floor (12.6 MB out / 6.3 TB/s = 1.9 us) -> done.
__global__ __launch_bounds__(256) void k_final(const float2* __restrict__ D,
                                               float* __restrict__ out) {
    __shared__ float2 partB[210];
    __shared__ float2 B[NF][2];                      // interleaved: [dq][branch] -> b128/dq
    const int x = blockIdx.x;
    const int t = threadIdx.x;
    if (t < 210) {                                   // 70 (b,dq) x 3 idp-segments of 23
        const int s = t / 70, r = t % 70, b = r / 35, dq = r % 35;
        float si, ci, ss, cc;
        sincospif((float)((23 * s - 34) * x) * (1.0f / 512.0f), &si, &ci);
        sincospif((float)x                   * (1.0f / 512.0f), &ss, &cc);
        const float tc = 2.0f * cc;
        float wr = ci, wi = si;
        float pr = ci * cc + si * ss;                // w_{-1}
        float pi = si * cc - ci * ss;
        float re = 0.0f, im = 0.0f;
        const int i0 = 23 * s;
        for (int idp = i0; idp < i0 + 23; ++idp) {
            float2 d = D[(b * NDP + idp) * NF + dq];
            re += d.x * wr - d.y * wi;
            im += d.x * wi + d.y * wr;
            float nr = tc * wr - pr;
            float ni = tc * wi - pi;
            pr = wr; pi = wi; wr = nr; wi = ni;
        }
        partB[t] = make_float2(re, im);
    }
    __syncthreads();
    if (t < 70) {
        float2 a = partB[t], b2 = partB[t + 70], c = partB[t + 140];
        B[t % 35][t / 35] = make_float2(a.x + b2.x + c.x, a.y + b2.y + c.y);
    }
    __syncthreads();
    const float bf0 = B[0][0].x;
    const float bd0 = B[0][1].x;
    float s1, c1;
    sincospif((float)t * (1.0f / 512.0f), &s1, &c1);
    const float tc = 2.0f * c1;
    float cx = c1, cy = s1;                          // w_1 = e(t)
    float px = 1.0f, py = 0.0f;                      // w_0
    float2 Sf[4] = {{0,0},{0,0},{0,0},{0,0}};
    float2 Sd[4] = {{0,0},{0,0},{0,0},{0,0}};
    #pragma unroll
    for (int dq = 1; dq < NF; ++dq) {
        const float2 bf = B[dq][0];
        const float2 bd = B[dq][1];
        const int mm = dq & 3;                       // compile-time under unroll
        Sf[mm].x += bf.x * cx - bf.y * cy;           // S_m += B[dq] * e(dq*t)
        Sf[mm].y += bf.x * cy + bf.y * cx;
        Sd[mm].x += bd.x * cx - bd.y * cy;
        Sd[mm].y += bd.x * cy + bd.y * cx;
        const float nx = tc * cx - px;               // Chebyshev advance
        const float ny = tc * cy - py;
        px = cx; py = cy; cx = nx; cy = ny;
    }
    // sf[j] = Re( sum_m S_m * i^(m*j) );  Re(S*i^s): s=0:+x 1:-y 2:-x 3:+y
    float sf[4], sd[4];
    sf[0] = Sf[0].x + Sf[1].x + Sf[2].x + Sf[3].x;
    sf[1] = Sf[0].x - Sf[1].y - Sf[2].x + Sf[3].y;
    sf[2] = Sf[0].x - Sf[1].x + Sf[2].x - Sf[3].x;
    sf[3] = Sf[0].x + Sf[1].y - Sf[2].x - Sf[3].y;
    sd[0] = Sd[0].x + Sd[1].x + Sd[2].x + Sd[3].x;
    sd[1] = Sd[0].x - Sd[1].y - Sd[2].x + Sd[3].y;
    sd[2] = Sd[0].x - Sd[1].x + Sd[2].x - Sd[3].x;
    sd[3] = Sd[0].x + Sd[1].y - Sd[2].x - Sd[3].y;
    #pragma unroll
    for (int j = 0; j < 4; ++j) {
        const float If = bf0 + 2.0f * sf[j];
        const float Id = bd0 + 2.0f * sd[j];
        const int o = x * WS + t + 256 * j;
        out[o]               = 1.0f / (1.0f + expf(-50.0f * (If - 0.225f)));
        out[o + HS * WS]     = 1.0f / (1.0f + expf(-50.0f * (1.0404f * If - 0.225f)));
        out[o + 2 * HS * WS] = 1.0f / (1.0f + expf(-50.0f * (Id - 0.225f)));
    }
}

extern "C" void kernel_launch(void* const* d_in, const int* in_sizes, int n_in,
                              void* d_out, int out_size, void* d_ws, size_t ws_size,
                              hipStream_t stream) {
    (void)in_sizes; (void)n_in; (void)out_size; (void)ws_size;
    const float* ms    = (const float*)d_in[0];
    const float* kf_re = (const float*)d_in[1];
    const float* kf_im = (const float*)d_in[2];
    const float* kd_re = (const float*)d_in[3];
    const float* kd_im = (const float*)d_in[4];
    const float* kf_sc = (const float*)d_in[5];
    const float* kd_sc = (const float*)d_in[6];

    char* ws = (char*)d_ws;
    float2* G      = (float2*)(ws + G_OFF);
    float2* crop   = (float2*)(ws + CROP_OFF);
    float2* D      = (float2*)(ws + D_OFF);
    unsigned long long* zq = (unsigned long long*)(ws + CROP_OFF);
    float* out     = (float*)d_out;

    k_maskG<<<HS, 256, 0, stream>>>(ms, G, zq);
    k_crop<<<NF * 16, 256, 0, stream>>>(G, crop);
    k_D<<<2 * KK * NGRP, 256, 0, stream>>>(crop, kf_re, kf_im, kd_re, kd_im, kf_sc, kd_sc, D);
    k_final<<<HS, 256, 0, stream>>>(D, out);
}

// Round 9
// 48.537 us; speedup vs baseline: 1.0290x; 1.0290x over previous
//
#include <hip/hip_runtime.h>
#include <math.h>

#define HS 1024
#define WS 1024
#define KK 24
#define KD 35
#define NF 35
#define NDP 69              // dp in [-34,34]
#define NGRP 16             // dp-groups per (b,k); grid = 2*24*16 = 768 = 3 blocks/CU
#define CROW 42             // padded C row stride (cols 35..41 = zero pad)
#define NCHUNK 38           // 5-u chunks over the triangular (dq-tile,u) domain
#define PRS 10              // partR per-lane stride (floats); even -> aligned float2

// ws byte offsets
#define G_OFF    0u                     // [35][1024] float2 = 286720 B
#define CROP_OFF 286720u                // [35][35] float2   = 9800 B
#define D_OFF    296520u                // [2][69][35] float2 = 38640 B
#define ZERO_QWORDS 6055                // (9800 + 38640) / 8, crop+D contiguous

// ---- K1: mask row x -> pool3+sigmoid -> column DFT (Hermitian: 18 freqs) ----
// Radix-4 fold + Chebyshev rotator advance (w_{n+1} = 2cos*w_n - w_{n-1}: 2 FMA vs 4).
// Also zeroes crop+D (blocks 0..23); kernel boundary makes it coherent for K2/K3.
__global__ __launch_bounds__(256) void k_maskG(const float* __restrict__ ms,
                                               float2* __restrict__ G,
                                               unsigned long long* __restrict__ zq) {
    __shared__ float cs[WS + 8];        // column sums at cs[4+j]; cs[3] and cs[4+WS] are zero guards
    __shared__ float m[WS];
    __shared__ float2 part[252];
    const int x = blockIdx.x;
    const int t = threadIdx.x;

    if (x < 24) {
        int i = x * 256 + t;
        if (i < ZERO_QWORDS) zq[i] = 0ull;
    }
    {   // vertical 3-sum, float4: each thread owns j = 4t..4t+3 (exactly covers WS)
        const int j = 4 * t;
        float4 b = *(const float4*)&ms[x * WS + j];
        float4 a = make_float4(0.f, 0.f, 0.f, 0.f);
        float4 d = make_float4(0.f, 0.f, 0.f, 0.f);
        if (x > 0)      a = *(const float4*)&ms[(x - 1) * WS + j];
        if (x < HS - 1) d = *(const float4*)&ms[(x + 1) * WS + j];
        float4 s;
        s.x = a.x + b.x + d.x;
        s.y = a.y + b.y + d.y;
        s.z = a.z + b.z + d.z;
        s.w = a.w + b.w + d.w;
        *(float4*)&cs[4 + j] = s;
        if (t == 0) { cs[3] = 0.0f; cs[4 + WS] = 0.0f; }
    }
    __syncthreads();
    {   // horizontal 3-sum + sigmoid, float4
        const int j = 4 * t;
        float4 c = *(const float4*)&cs[4 + j];
        float l = cs[3 + j];
        float r = cs[8 + j];
        float p0 = (l   + c.x + c.y) * (1.0f / 9.0f);
        float p1 = (c.x + c.y + c.z) * (1.0f / 9.0f);
        float p2 = (c.y + c.z + c.w) * (1.0f / 9.0f);
        float p3 = (c.z + c.w + r  ) * (1.0f / 9.0f);
        float4 mv;
        mv.x = 1.0f / (1.0f + expf(-4.0f * (p0 - 0.5f)));
        mv.y = 1.0f / (1.0f + expf(-4.0f * (p1 - 0.5f)));
        mv.z = 1.0f / (1.0f + expf(-4.0f * (p2 - 0.5f)));
        mv.w = 1.0f / (1.0f + expf(-4.0f * (p3 - 0.5f)));
        *(float4*)&m[j] = mv;
    }
    __syncthreads();
    if (t < 252) {                                   // 18 freqs (v=0..17) x 14 segments
        const int qi = t / 14, seg = t % 14;
        float si, ci, ss, cc;
        sincospif(-(float)(qi * seg) * (1.0f / 512.0f), &si, &ci);
        sincospif(-(float)(qi * 14)  * (1.0f / 512.0f), &ss, &cc);
        const float s2 = (qi & 1) ? -1.0f : 1.0f;    // (-1)^qi
        const int qm = qi & 3;                       // e1 = (-i)^qi
        const float er = (qm == 0) ? 1.0f : (qm == 2) ? -1.0f : 0.0f;
        const float ei = (qm == 1) ? -1.0f : (qm == 3) ? 1.0f : 0.0f;
        const float tc = 2.0f * cc;                  // Chebyshev coefficient
        float wr = ci, wi = si;                      // w_0
        float pr = ci * cc + si * ss;                // w_{-1} = w_0 * conj(step)
        float pi = si * cc - ci * ss;
        float re = 0.0f, im = 0.0f;
        for (int y = seg; y < 256; y += 14) {
            float m0 = m[y], m1 = m[y + 256], m2 = m[y + 512], m3 = m[y + 768];
            float A  = fmaf(s2, m2, m0);             // fold = (m0 + s2 m2) + e1*(m1 + s2 m3)
            float Bv = fmaf(s2, m3, m1);
            float tre = fmaf(er, Bv, A);
            float tim = ei * Bv;
            re += tre * wr - tim * wi;               // (fold) * w^y
            im += tre * wi + tim * wr;
            float nr = tc * wr - pr;                 // Chebyshev advance
            float ni = tc * wi - pi;
            pr = wr; pi = wi; wr = nr; wi = ni;
        }
        part[t] = make_float2(re, im);
    }
    __syncthreads();
    if (t < 18) {
        float re = 0.0f, im = 0.0f;
        for (int s = 0; s < 14; ++s) { float2 p = part[t * 14 + s]; re += p.x; im += p.y; }
        G[(17 + t) * HS + x] = make_float2(re, im);
        if (t > 0) G[(17 - t) * HS + x] = make_float2(re, -im);   // Hermitian mirror (m real)
    }
}

// ---- K2: crop[p][q] += partial DFT over 64-long x-segment (35 q x 16 segs = 560 blocks) ----
// Chebyshev rotator; 16 segments (32 regressed in R5 -> atomic contention suspect).
__global__ __launch_bounds__(256) void k_crop(const float2* __restrict__ G,
                                              float2* __restrict__ crop) {
    __shared__ float2 g2[64];
    __shared__ float2 part[245];
    const int q  = blockIdx.x >> 4;
    const int xs = (blockIdx.x & 15) * 64;
    const int t  = threadIdx.x;
    if (t < 64) g2[t] = G[q * HS + xs + t];
    __syncthreads();
    if (t < 245) {
        const int p = t / 7, seg = t % 7;
        const int v = p - 17;
        float si, ci, ss, cc;
        sincospif((float)(v * (xs + seg)) * (1.0f / 512.0f), &si, &ci);
        sincospif((float)(v * 7)          * (1.0f / 512.0f), &ss, &cc);
        const float tc = 2.0f * cc;
        float wr = ci, wi = si;
        float pr = ci * cc + si * ss;                // w_{-1}
        float pi = si * cc - ci * ss;
        float re = 0.0f, im = 0.0f;
        for (int r = seg; r < 64; r += 7) {
            float2 gv = g2[r];
            re += gv.x * wr + gv.y * wi;     // g * conj(w)
            im += gv.y * wr - gv.x * wi;
            float nr = tc * wr - pr;
            float ni = tc * wi - pi;
            pr = wr; pi = wi; wr = nr; wi = ni;
        }
        part[t] = make_float2(re, im);
    }
    __syncthreads();
    if (t < NF) {
        float re = 0.0f, im = 0.0f;
        for (int s = 0; s < 7; ++s) { float2 p2 = part[t * 7 + s]; re += p2.x; im += p2.y; }
        float* dst = (float*)&crop[t * NF + q];
        atomicAdd(dst,     re);              // device-scope -> coherent point
        atomicAdd(dst + 1, im);
    }
}

// ---- K3: D[b][dp][dq] += sk * autocorr(C); block = (b,k,dp-group) ----
// Flattened chunk list, lane = chunk*6+pgrp, 228 equal-work lanes, p-stride 6; sliding
// window (2 LDS reads / 4 cMACs); partR double-buffered, 1 barrier/dp; reduce on
// wave 0. (Closed axis: all-waves reduce (R5) and round-robin reduce + NGRP=23 (R8)
// both regressed vs this simple form.)
__global__ __launch_bounds__(256) void k_D(
    const float2* __restrict__ crop,
    const float* __restrict__ kre0, const float* __restrict__ kim0,
    const float* __restrict__ kre1, const float* __restrict__ kim1,
    const float* __restrict__ sc0,  const float* __restrict__ sc1,
    float2* __restrict__ D)
{
    __shared__ float2 C[KD * CROW];
    __shared__ float partRf[2][NCHUNK * 6 * PRS];    // [buf][lane*PRS + 2c(+1)]
    const int tup = blockIdx.x;
    const int t   = threadIdx.x;

    const int b   = tup / (KK * NGRP);
    const int rem = tup % (KK * NGRP);
    const int k   = rem / NGRP;
    const int g   = rem % NGRP;
    const float* kre = b ? kre1 : kre0;
    const float* kim = b ? kim1 : kim0;
    const float dosefac = (b ? 0.98f : 1.0f) * (1.0f / 1048576.0f);
    const float sk2 = ((b ? sc1 : sc0)[k]) * dosefac * dosefac;   // dose^2 / N^4 folded

    // zero the C pad (cols 35..41); products against pad vanish -> no bound checks
    if (t < 245) C[(t / 7) * CROW + 35 + (t % 7)] = make_float2(0.0f, 0.0f);
    #pragma unroll
    for (int j = 0; j < 5; ++j) {                // stage C = crop .* kernel (unscaled)
        int i = t + j * 256;
        if (i < KD * KD) {
            float2 c = crop[i];                  // global, L2-cached across blocks
            int row = i / 35, col = i % 35;
            float kr = kre[k * KD * KD + i], ki = kim[k * KD * KD + i];
            C[row * CROW + col] = make_float2(c.x * kr - c.y * ki,
                                              c.x * ki + c.y * kr);
        }
    }
    __syncthreads();

    // lane -> (chunk, pgrp); chunk -> (tau, uchunk) via cb = {0,7,14,20,25,29,32,35,37}
    const int ch = t / 6;
    const int pg = t % 6;
    const bool act = (ch < NCHUNK);
    const int tau = (ch >= 7) + (ch >= 14) + (ch >= 20) + (ch >= 25)
                  + (ch >= 29) + (ch >= 32) + (ch >= 35) + (ch >= 37);
    const int cbt = (tau == 0) ? 0 : (tau == 1) ? 7 : (tau == 2) ? 14 : (tau == 3) ? 20
                  : (tau == 4) ? 25 : (tau == 5) ? 29 : (tau == 6) ? 32 : (tau == 7) ? 35 : 37;
    const int d0 = 4 * tau;
    const int u0 = 5 * (ch - cbt);               // act => d0+u0+7 <= 41 (pad bound)

    // reduce-lane lookup (dq = t): contiguous partR rows [cb*6, (cb+nch)*6)
    const int tau2 = t >> 2;
    const int cb2 = (tau2 == 0) ? 0 : (tau2 == 1) ? 7 : (tau2 == 2) ? 14 : (tau2 == 3) ? 20
                  : (tau2 == 4) ? 25 : (tau2 == 5) ? 29 : (tau2 == 6) ? 32 : (tau2 == 7) ? 35 : 37;
    const int cn2 = (tau2 == 0) ? 7 : (tau2 == 1) ? 7 : (tau2 == 2) ? 6 : (tau2 == 3) ? 5
                  : (tau2 == 4) ? 4 : (tau2 == 5) ? 3 : (tau2 == 6) ? 3 : (tau2 == 7) ? 2 : 1;
    const int s0 = cb2 * 6, cnt = cn2 * 6, c2 = (t & 3) * 2;

    int pb = 0;
    for (int idp = g; idp < NDP; idp += NGRP) {
        const int dp = idp - 34;
        if (act) {
            const int plo = max(0, dp), phi = min(34, 34 + dp);
            float2 ac0 = {0,0}, ac1 = {0,0}, ac2 = {0,0}, ac3 = {0,0};
            for (int p = plo + pg; p <= phi; p += 6) {
                const float2* rowa = &C[p * CROW + d0 + u0];
                const float2* rowb = &C[(p - dp) * CROW + u0];
                float2 a0 = rowa[0], a1 = rowa[1], a2 = rowa[2];
                #pragma unroll
                for (int s = 0; s < 5; ++s) {
                    float2 a3 = rowa[s + 3];     // max col 41 -> pad, zero
                    float2 bb = rowb[s];         // max col 34 -> real; a-pad kills overrun
                    ac0.x += a0.x * bb.x + a0.y * bb.y;  ac0.y += a0.y * bb.x - a0.x * bb.y;
                    ac1.x += a1.x * bb.x + a1.y * bb.y;  ac1.y += a1.y * bb.x - a1.x * bb.y;
                    ac2.x += a2.x * bb.x + a2.y * bb.y;  ac2.y += a2.y * bb.x - a2.x * bb.y;
                    ac3.x += a3.x * bb.x + a3.y * bb.y;  ac3.y += a3.y * bb.x - a3.x * bb.y;
                    a0 = a1; a1 = a2; a2 = a3;   // window shift (renamed away by unroll)
                }
            }
            float* pr = &partRf[pb][t * PRS];
            *(float2*)&pr[0] = ac0;
            *(float2*)&pr[2] = ac1;
            *(float2*)&pr[4] = ac2;
            *(float2*)&pr[6] = ac3;
        }
        __syncthreads();
        if (t < NF) {                            // dq = t
            float re = 0.0f, im = 0.0f;
            for (int j = 0; j < cnt; ++j) {
                const float2 v = *(const float2*)&partRf[pb][(s0 + j) * PRS + c2];
                re += v.x; im += v.y;
            }
            float* dst = (float*)&D[(b * NDP + idp) * NF + t];
            atomicAdd(dst,     re * sk2);
            atomicAdd(dst + 1, im * sk2);
        }
        pb ^= 1;                                 // next iter writes other buf; its barrier
    }                                            // protects this buf before re-write
}

// ---- K4: per row x: B_x[dq] = sum_dp D[dp][dq] e(dp x) (3-way split); then pixels ----
// Pixels y = t + 256j: e(dq*y) = e(dq*t) * i^(dq*j). Accumulate S[dq&3] directly;
// apply the i^(m*j) twist once in the epilogue. Chebyshev rotator in both phases.
// Per dq in the pixel loop: 8 FMA accum + 2 cheb + 1 b128 read = 11 insts.
// NOTE: k_final is at its HBM write floor (12.6 MB out / 6.3 TB/s = 1.9 us) -> done.
__global__ __launch_bounds__(256) void k_final(const float2* __restrict__ D,
                                               float* __restrict__ out) {
    __shared__ float2 partB[210];
    __shared__ float2 B[NF][2];                      // interleaved: [dq][branch] -> b128/dq
    const int x = blockIdx.x;
    const int t = threadIdx.x;
    if (t < 210) {                                   // 70 (b,dq) x 3 idp-segments of 23
        const int s = t / 70, r = t % 70, b = r / 35, dq = r % 35;
        float si, ci, ss, cc;
        sincospif((float)((23 * s - 34) * x) * (1.0f / 512.0f), &si, &ci);
        sincospif((float)x                   * (1.0f / 512.0f), &ss, &cc);
        const float tc = 2.0f * cc;
        float wr = ci, wi = si;
        float pr = ci * cc + si * ss;                // w_{-1}
        float pi = si * cc - ci * ss;
        float re = 0.0f, im = 0.0f;
        const int i0 = 23 * s;
        for (int idp = i0; idp < i0 + 23; ++idp) {
            float2 d = D[(b * NDP + idp) * NF + dq];
            re += d.x * wr - d.y * wi;
            im += d.x * wi + d.y * wr;
            float nr = tc * wr - pr;
            float ni = tc * wi - pi;
            pr = wr; pi = wi; wr = nr; wi = ni;
        }
        partB[t] = make_float2(re, im);
    }
    __syncthreads();
    if (t < 70) {
        float2 a = partB[t], b2 = partB[t + 70], c = partB[t + 140];
        B[t % 35][t / 35] = make_float2(a.x + b2.x + c.x, a.y + b2.y + c.y);
    }
    __syncthreads();
    const float bf0 = B[0][0].x;
    const float bd0 = B[0][1].x;
    float s1, c1;
    sincospif((float)t * (1.0f / 512.0f), &s1, &c1);
    const float tc = 2.0f * c1;
    float cx = c1, cy = s1;                          // w_1 = e(t)
    float px = 1.0f, py = 0.0f;                      // w_0
    float2 Sf[4] = {{0,0},{0,0},{0,0},{0,0}};
    float2 Sd[4] = {{0,0},{0,0},{0,0},{0,0}};
    #pragma unroll
    for (int dq = 1; dq < NF; ++dq) {
        const float2 bf = B[dq][0];
        const float2 bd = B[dq][1];
        const int mm = dq & 3;                       // compile-time under unroll
        Sf[mm].x += bf.x * cx - bf.y * cy;           // S_m += B[dq] * e(dq*t)
        Sf[mm].y += bf.x * cy + bf.y * cx;
        Sd[mm].x += bd.x * cx - bd.y * cy;
        Sd[mm].y += bd.x * cy + bd.y * cx;
        const float nx = tc * cx - px;               // Chebyshev advance
        const float ny = tc * cy - py;
        px = cx; py = cy; cx = nx; cy = ny;
    }
    // sf[j] = Re( sum_m S_m * i^(m*j) );  Re(S*i^s): s=0:+x 1:-y 2:-x 3:+y
    float sf[4], sd[4];
    sf[0] = Sf[0].x + Sf[1].x + Sf[2].x + Sf[3].x;
    sf[1] = Sf[0].x - Sf[1].y - Sf[2].x + Sf[3].y;
    sf[2] = Sf[0].x - Sf[1].x + Sf[2].x - Sf[3].x;
    sf[3] = Sf[0].x + Sf[1].y - Sf[2].x - Sf[3].y;
    sd[0] = Sd[0].x + Sd[1].x + Sd[2].x + Sd[3].x;
    sd[1] = Sd[0].x - Sd[1].y - Sd[2].x + Sd[3].y;
    sd[2] = Sd[0].x - Sd[1].x + Sd[2].x - Sd[3].x;
    sd[3] = Sd[0].x + Sd[1].y - Sd[2].x - Sd[3].y;
    #pragma unroll
    for (int j = 0; j < 4; ++j) {
        const float If = bf0 + 2.0f * sf[j];
        const float Id = bd0 + 2.0f * sd[j];
        const int o = x * WS + t + 256 * j;
        out[o]               = 1.0f / (1.0f + expf(-50.0f * (If - 0.225f)));
        out[o + HS * WS]     = 1.0f / (1.0f + expf(-50.0f * (1.0404f * If - 0.225f)));
        out[o + 2 * HS * WS] = 1.0f / (1.0f + expf(-50.0f * (Id - 0.225f)));
    }
}

extern "C" void kernel_launch(void* const* d_in, const int* in_sizes, int n_in,
                              void* d_out, int out_size, void* d_ws, size_t ws_size,
                              hipStream_t stream) {
    (void)in_sizes; (void)n_in; (void)out_size; (void)ws_size;
    const float* ms    = (const float*)d_in[0];
    const float* kf_re = (const float*)d_in[1];
    const float* kf_im = (const float*)d_in[2];
    const float* kd_re = (const float*)d_in[3];
    const float* kd_im = (const float*)d_in[4];
    const float* kf_sc = (const float*)d_in[5];
    const float* kd_sc = (const float*)d_in[6];

    char* ws = (char*)d_ws;
    float2* G      = (float2*)(ws + G_OFF);
    float2* crop   = (float2*)(ws + CROP_OFF);
    float2* D      = (float2*)(ws + D_OFF);
    unsigned long long* zq = (unsigned long long*)(ws + CROP_OFF);
    float* out     = (float*)d_out;

    k_maskG<<<HS, 256, 0, stream>>>(ms, G, zq);
    k_crop<<<NF * 16, 256, 0, stream>>>(G, crop);
    k_D<<<2 * KK * NGRP, 256, 0, stream>>>(crop, kf_re, kf_im, kd_re, kd_im, kf_sc, kd_sc, D);
    k_final<<<HS, 256, 0, stream>>>(D, out);
}